// Round 6
// baseline (226.627 us; speedup 1.0000x reference)
//
#include <hip/hip_runtime.h>
#include <math.h>

#define N 512
#define C 157
#define M 20
#define NWAVE 16      // 1024 threads

typedef float float4a __attribute__((ext_vector_type(4), aligned(4)));
typedef float float4s __attribute__((ext_vector_type(4), aligned(16)));

__device__ __forceinline__ float sigmoidf_(float x) {
    return 1.0f / (1.0f + __expf(-x));
}

__global__ __launch_bounds__(1024, 8) void atf_main_kernel(
    const float* __restrict__ a,
    const float* __restrict__ aa,
    const float* __restrict__ target,
    const float* __restrict__ bank_values,
    const int* __restrict__ bank_times,
    const int* __restrict__ bank_mask,   // jax bool -> harness int32
    const int* __restrict__ ids,
    const int* __restrict__ times,
    float* __restrict__ out,             // qa [N*C]
    float* __restrict__ loss_part)       // [N]
{
    const int n    = blockIdx.x;
    const int tid  = threadIdx.x;
    const int wave = tid >> 6;
    const int lane = tid & 63;

    __shared__ float s_ts[M];
    __shared__ int   s_mk[M];
    __shared__ float s_msg[C];
    __shared__ alignas(16) float s_fmsg[C];
    __shared__ float s_rowp[8][C];               // shuffle-seg partials (stride 157: conflict-free)
    __shared__ alignas(16) float s_colp[NWAVE][160];  // padded row for aligned b128 writes
    __shared__ float s_red[NWAVE];

    const int   id = ids[n];
    const float t0 = (float)times[n];

    if (tid < M) {
        s_ts[tid] = (float)bank_times[(size_t)id * M + tid];
        s_mk[tid] = (bank_mask[(size_t)id * M + tid] != 0) ? 1 : 0;
    }
    __syncthreads();

    // ---- phase 1: msg / fmsg ----
    if (tid < C) {
        const float inv2s2 = 1.0f / (2.0f * 300.0f * 300.0f);
        const float INVDEC = 1.0f / 0.9f;
        float accP = 0.f, accF = 0.f, denP = 0.f, denF = 0.f;
        float wP = 1.f, wF = 1.f;
        const float* vb = bank_values + (size_t)id * M * C + tid;
        #pragma unroll
        for (int m = 0; m < M; ++m) {
            const float ts = s_ts[m];
            const float d  = ts - t0;
            const float kern = __expf(-d * d * inv2s2);
            const float v = vb[m * C];
            const bool mk = (s_mk[m] != 0);
            if (mk && ts < t0) { accP += wP * kern * v; denP += wP; wP *= INVDEC; }
            if (mk && ts > t0) { accF += wF * kern * v; denF += wF; wF *= INVDEC; }
        }
        s_msg[tid]  = (denP > 0.f) ? accP / fmaxf(denP, 1e-7f) : 0.0f;
        s_fmsg[tid] = (denF > 0.f) ? accF / fmaxf(denF, 1e-7f) : 0.0f;
    }
    __syncthreads();

    // ---- phase 2: both einsums, lane = 4 consecutive j's, wave = rows ----
    const float* aan = aa + (size_t)n * C * C;
    float4s f4 = {0.f, 0.f, 0.f, 0.f};
    if (lane < 39)       f4 = *(const float4s*)&s_fmsg[4 * lane];
    else if (lane == 39) f4.x = s_fmsg[156];

    float c0 = 0.f, c1 = 0.f, c2 = 0.f, c3 = 0.f;

    for (int i = wave; i < C; i += 2 * NWAVE) {
        const int ib = i + NWAVE;
        const float* rA = aan + i * C;
        float4a vA = {0.f, 0.f, 0.f, 0.f};
        if (lane < 39)       vA = *(const float4a*)(rA + 4 * lane);
        else if (lane == 39) vA.x = rA[156];
        const float mA = s_msg[i];

        float4a vB = {0.f, 0.f, 0.f, 0.f};
        float mB = 0.f;
        if (ib < C) {
            const float* rB = aan + ib * C;
            if (lane < 39)       vB = *(const float4a*)(rB + 4 * lane);
            else if (lane == 39) vB.x = rB[156];
            mB = s_msg[ib];
        }

        c0 += vA.x * mA + vB.x * mB;
        c1 += vA.y * mA + vB.y * mB;
        c2 += vA.z * mA + vB.z * mB;
        c3 += vA.w * mA + vB.w * mB;

        float rpA = vA.x * f4.x + vA.y * f4.y + vA.z * f4.z + vA.w * f4.w;
        float rpB = vB.x * f4.x + vB.y * f4.y + vB.z * f4.z + vB.w * f4.w;
        // 3-step dual reduction: lanes 0-7 end with partials over lanes ≡ k (mod 8)
        rpA += __shfl_down(rpA, 32, 64);  rpB += __shfl_down(rpB, 32, 64);
        rpA += __shfl_down(rpA, 16, 64);  rpB += __shfl_down(rpB, 16, 64);
        rpA += __shfl_down(rpA,  8, 64);  rpB += __shfl_down(rpB,  8, 64);
        if (lane < 8) {
            s_rowp[lane][i] = rpA;
            if (ib < C) s_rowp[lane][ib] = rpB;
        }
    }
    if (lane < 39) {
        float4s cv = {c0, c1, c2, c3};
        *(float4s*)&s_colp[wave][4 * lane] = cv;
    } else if (lane == 39) {
        s_colp[wave][156] = c0;
    }
    __syncthreads();

    // ---- phase 3: epilogue ----
    float local = 0.0f;
    if (tid < C) {
        float colsum = 0.0f;
        #pragma unroll
        for (int w = 0; w < NWAVE; ++w) colsum += s_colp[w][tid];
        float rowsum = 0.0f;
        #pragma unroll
        for (int k = 0; k < 8; ++k) rowsum += s_rowp[k][tid];

        const float av = a[(size_t)n * C + tid];
        const float qlin = av + colsum + rowsum;
        const float p = sigmoidf_(qlin);
        out[(size_t)n * C + tid] = p;

        const float t = target[(size_t)n * C + tid];
        float pc = fminf(fmaxf(p, 1e-7f), 1.0f - 1e-7f);
        float pa = sigmoidf_(av);
        pa = fminf(fmaxf(pa, 1e-7f), 1.0f - 1e-7f);
        local = t * logf(pc) + (1.0f - t) * logf(1.0f - pc)
              + t * logf(pa) + (1.0f - t) * logf(1.0f - pa);
    }
    #pragma unroll
    for (int off = 32; off > 0; off >>= 1) local += __shfl_down(local, off, 64);
    if (lane == 0) s_red[wave] = local;
    __syncthreads();
    if (tid == 0) {
        float s = 0.0f;
        #pragma unroll
        for (int w = 0; w < NWAVE; ++w) s += s_red[w];
        loss_part[n] = s;
    }
}

__global__ __launch_bounds__(256) void atf_finalize_kernel(
    const float* __restrict__ loss_part,
    float* __restrict__ out)
{
    const int tid  = threadIdx.x;
    const int wave = tid >> 6;
    const int lane = tid & 63;
    __shared__ double s_red[4];

    double local = (double)loss_part[tid] + (double)loss_part[tid + 256];
    #pragma unroll
    for (int off = 32; off > 0; off >>= 1) local += __shfl_down(local, off, 64);
    if (lane == 0) s_red[wave] = local;
    __syncthreads();
    if (tid == 0) {
        const double s = s_red[0] + s_red[1] + s_red[2] + s_red[3];
        out[N * C] = (float)(-s / ((double)(N * C) * 3.0));
    }
}

extern "C" void kernel_launch(void* const* d_in, const int* in_sizes, int n_in,
                              void* d_out, int out_size, void* d_ws, size_t ws_size,
                              hipStream_t stream) {
    const float* a           = (const float*)d_in[0];
    const float* aa          = (const float*)d_in[1];
    const float* target      = (const float*)d_in[2];
    const float* bank_values = (const float*)d_in[3];
    const int*   bank_times  = (const int*)d_in[4];
    const int*   bank_mask   = (const int*)d_in[5];
    const int*   ids         = (const int*)d_in[6];
    const int*   times       = (const int*)d_in[7];

    float* out       = (float*)d_out;
    float* loss_part = (float*)d_ws;   // 512 floats

    atf_main_kernel<<<N, 1024, 0, stream>>>(a, aa, target, bank_values, bank_times,
                                            bank_mask, ids, times, out, loss_part);
    atf_finalize_kernel<<<1, 256, 0, stream>>>(loss_part, out);
}

// Round 7
// 203.464 us; speedup vs baseline: 1.1138x; 1.1138x over previous
//
#include <hip/hip_runtime.h>
#include <math.h>

#define N 512
#define C 157
#define M 20
#define NW 8   // waves per block (512 threads)

__device__ __forceinline__ float sigmoidf_(float x) {
    return 1.0f / (1.0f + __expf(-x));
}

__global__ __launch_bounds__(512) void atf_main_kernel(
    const float* __restrict__ a,
    const float* __restrict__ aa,
    const float* __restrict__ target,
    const float* __restrict__ bank_values,
    const int* __restrict__ bank_times,
    const int* __restrict__ bank_mask,   // jax bool -> harness int32
    const int* __restrict__ ids,
    const int* __restrict__ times,
    float* __restrict__ out,             // qa [N*C]
    float* __restrict__ loss_part)       // [N]
{
    const int n    = blockIdx.x;
    const int tid  = threadIdx.x;
    const int wave = tid >> 6;
    const int lane = tid & 63;

    __shared__ float s_ts[M];
    __shared__ int   s_mk[M];
    __shared__ float s_msg[C];
    __shared__ float s_fmsg[C];
    __shared__ float s_rowp[8][C];      // 3-step shuffle partials (29k mod 32 distinct -> conflict-free)
    __shared__ float s_colp[NW][C];
    __shared__ float s_red[NW];

    const int   id = ids[n];
    const float t0 = (float)times[n];

    const float* aan = aa + (size_t)n * C * C;
    const int j0 = lane, j1 = lane + 64, j2 = lane + 128;
    const bool ok1 = (j1 < C), ok2 = (j2 < C);

    // ---- prefetch first row pair (rows wave, wave+8) before any barrier ----
    float a0, a1, a2, b0, b1, b2;
    {
        const float* rA = aan + wave * C;
        a0 = rA[j0]; a1 = ok1 ? rA[j1] : 0.0f; a2 = ok2 ? rA[j2] : 0.0f;
        const float* rB = aan + (wave + NW) * C;
        b0 = rB[j0]; b1 = ok1 ? rB[j1] : 0.0f; b2 = ok2 ? rB[j2] : 0.0f;
    }
    // ---- prefetch epilogue inputs ----
    float av = 0.0f, tv = 0.0f;
    if (tid < C) {
        av = a[(size_t)n * C + tid];
        tv = target[(size_t)n * C + tid];
    }

    if (tid < M) {
        s_ts[tid] = (float)bank_times[(size_t)id * M + tid];
        s_mk[tid] = (bank_mask[(size_t)id * M + tid] != 0) ? 1 : 0;
    }
    __syncthreads();

    // ---- phase 1: msg / fmsg ----
    if (tid < C) {
        const float inv2s2 = 1.0f / (2.0f * 300.0f * 300.0f);
        const float INVDEC = 1.0f / 0.9f;
        float accP = 0.f, accF = 0.f, denP = 0.f, denF = 0.f;
        float wP = 1.f, wF = 1.f;
        const float* vb = bank_values + (size_t)id * M * C + tid;
        #pragma unroll
        for (int m = 0; m < M; ++m) {
            const float ts = s_ts[m];
            const float d  = ts - t0;
            const float kern = __expf(-d * d * inv2s2);
            const float v = vb[m * C];
            const bool mk = (s_mk[m] != 0);
            if (mk && ts < t0) { accP += wP * kern * v; denP += wP; wP *= INVDEC; }
            if (mk && ts > t0) { accF += wF * kern * v; denF += wF; wF *= INVDEC; }
        }
        s_msg[tid]  = (denP > 0.f) ? accP / fmaxf(denP, 1e-7f) : 0.0f;
        s_fmsg[tid] = (denF > 0.f) ? accF / fmaxf(denF, 1e-7f) : 0.0f;
    }
    __syncthreads();

    // ---- phase 2: software-pipelined, 2 rows/iter/wave, 3-step reductions ----
    float col0 = 0.f, col1 = 0.f, col2 = 0.f;
    const float f0 = s_fmsg[j0];
    const float f1 = ok1 ? s_fmsg[j1] : 0.0f;
    const float f2 = ok2 ? s_fmsg[j2] : 0.0f;

    for (int i = wave; i < C; ) {
        const int inext = i + 2 * NW;
        // prefetch next pair
        float na0 = 0.f, na1 = 0.f, na2 = 0.f, nb0 = 0.f, nb1 = 0.f, nb2 = 0.f;
        if (inext < C) {
            const float* rA = aan + inext * C;
            na0 = rA[j0]; na1 = ok1 ? rA[j1] : 0.0f; na2 = ok2 ? rA[j2] : 0.0f;
            const int ibn = inext + NW;
            if (ibn < C) {
                const float* rB = aan + ibn * C;
                nb0 = rB[j0]; nb1 = ok1 ? rB[j1] : 0.0f; nb2 = ok2 ? rB[j2] : 0.0f;
            }
        }
        // compute current pair (i, i+NW)
        const int ib = i + NW;
        const float mA = s_msg[i];
        const float mB = (ib < C) ? s_msg[ib] : 0.0f;

        col0 += a0 * mA + b0 * mB;
        col1 += a1 * mA + b1 * mB;
        col2 += a2 * mA + b2 * mB;

        float rpA = a0 * f0 + a1 * f1 + a2 * f2;
        float rpB = b0 * f0 + b1 * f1 + b2 * f2;
        rpA += __shfl_down(rpA, 32, 64);  rpB += __shfl_down(rpB, 32, 64);
        rpA += __shfl_down(rpA, 16, 64);  rpB += __shfl_down(rpB, 16, 64);
        rpA += __shfl_down(rpA,  8, 64);  rpB += __shfl_down(rpB,  8, 64);
        if (lane < 8) {
            s_rowp[lane][i] = rpA;
            if (ib < C) s_rowp[lane][ib] = rpB;
        }
        a0 = na0; a1 = na1; a2 = na2;
        b0 = nb0; b1 = nb1; b2 = nb2;
        i = inext;
    }
    s_colp[wave][j0] = col0;
    if (ok1) s_colp[wave][j1] = col1;
    if (ok2) s_colp[wave][j2] = col2;
    __syncthreads();

    // ---- phase 3: epilogue ----
    float local = 0.0f;
    if (tid < C) {
        float colsum = 0.0f;
        #pragma unroll
        for (int w = 0; w < NW; ++w) colsum += s_colp[w][tid];
        float rowsum = 0.0f;
        #pragma unroll
        for (int k = 0; k < 8; ++k) rowsum += s_rowp[k][tid];

        const float qlin = av + colsum + rowsum;
        const float p = sigmoidf_(qlin);
        out[(size_t)n * C + tid] = p;

        float pc = fminf(fmaxf(p, 1e-7f), 1.0f - 1e-7f);
        float pa = sigmoidf_(av);
        pa = fminf(fmaxf(pa, 1e-7f), 1.0f - 1e-7f);
        local = tv * logf(pc) + (1.0f - tv) * logf(1.0f - pc)
              + tv * logf(pa) + (1.0f - tv) * logf(1.0f - pa);
    }
    #pragma unroll
    for (int off = 32; off > 0; off >>= 1) local += __shfl_down(local, off, 64);
    if (lane == 0) s_red[wave] = local;
    __syncthreads();
    if (tid == 0) {
        float s = 0.0f;
        #pragma unroll
        for (int w = 0; w < NW; ++w) s += s_red[w];
        loss_part[n] = s;
    }
}

__global__ __launch_bounds__(256) void atf_finalize_kernel(
    const float* __restrict__ loss_part,
    float* __restrict__ out)
{
    const int tid  = threadIdx.x;
    const int wave = tid >> 6;
    const int lane = tid & 63;
    __shared__ double s_red[4];

    double local = (double)loss_part[tid] + (double)loss_part[tid + 256];
    #pragma unroll
    for (int off = 32; off > 0; off >>= 1) local += __shfl_down(local, off, 64);
    if (lane == 0) s_red[wave] = local;
    __syncthreads();
    if (tid == 0) {
        const double s = s_red[0] + s_red[1] + s_red[2] + s_red[3];
        out[N * C] = (float)(-s / ((double)(N * C) * 3.0));
    }
}

extern "C" void kernel_launch(void* const* d_in, const int* in_sizes, int n_in,
                              void* d_out, int out_size, void* d_ws, size_t ws_size,
                              hipStream_t stream) {
    const float* a           = (const float*)d_in[0];
    const float* aa          = (const float*)d_in[1];
    const float* target      = (const float*)d_in[2];
    const float* bank_values = (const float*)d_in[3];
    const int*   bank_times  = (const int*)d_in[4];
    const int*   bank_mask   = (const int*)d_in[5];
    const int*   ids         = (const int*)d_in[6];
    const int*   times       = (const int*)d_in[7];

    float* out       = (float*)d_out;
    float* loss_part = (float*)d_ws;   // 512 floats

    atf_main_kernel<<<N, 512, 0, stream>>>(a, aa, target, bank_values, bank_times,
                                           bank_mask, ids, times, out, loss_part);
    atf_finalize_kernel<<<1, 256, 0, stream>>>(loss_part, out);
}